// Round 4
// baseline (598.371 us; speedup 1.0000x reference)
//
#include <hip/hip_runtime.h>
#include <hip/hip_bf16.h>
#include <cstdint>
#include <cstddef>

using bf16 = __bf16;
typedef __bf16 bf16x8 __attribute__((ext_vector_type(8)));
typedef __bf16 bf16x4 __attribute__((ext_vector_type(4)));
typedef float  f32x4  __attribute__((ext_vector_type(4)));

#define DEV __device__ __forceinline__

DEV float sigmoidf_(float x) { return 1.0f / (1.0f + __expf(-x)); }

typedef __attribute__((address_space(1))) void as1_void;
typedef __attribute__((address_space(3))) void as3_void;

// async global->LDS, 16B per lane; LDS dest = wave-uniform base + lane*16
DEV void load16_lds(const void* g, void* l) {
  __builtin_amdgcn_global_load_lds((as1_void*)(void*)g, (as3_void*)l, 16, 0, 0);
}

#define SBAR()   __builtin_amdgcn_s_barrier()
#define SCHED0() __builtin_amdgcn_sched_barrier(0)

// ---------------- kernel 1: rmsnorm -> x (bf16) ----------------
__global__ __launch_bounds__(256) void k_rms_x(const float* __restrict__ inp,
                                               const float* __restrict__ nw,
                                               bf16* __restrict__ x) {
  const int row = blockIdx.x;            // b*S + s
  const int t = threadIdx.x;
  const float* r = inp + (size_t)row * 1024 + t * 4;
  f32x4 v = *(const f32x4*)r;
  float ss = v[0]*v[0] + v[1]*v[1] + v[2]*v[2] + v[3]*v[3];
  __shared__ float red[4];
  for (int off = 32; off; off >>= 1) ss += __shfl_down(ss, off);
  if ((t & 63) == 0) red[t >> 6] = ss;
  __syncthreads();
  float tot = red[0] + red[1] + red[2] + red[3];
  float sc = rsqrtf(tot * (1.0f / 1024.0f) + 1e-5f);
  f32x4 w = *(const f32x4*)(nw + t * 4);
  bf16x4 o;
  o[0] = (bf16)(v[0] * sc * w[0]); o[1] = (bf16)(v[1] * sc * w[1]);
  o[2] = (bf16)(v[2] * sc * w[2]); o[3] = (bf16)(v[3] * sc * w[3]);
  *(bf16x4*)(x + (size_t)row * 1024 + t * 4) = o;
}

// ---------------- kernel 2: column partial sums of x ----------------
__global__ __launch_bounds__(256) void k_colsum(const bf16* __restrict__ x,
                                                float* __restrict__ part) {
  const int b = blockIdx.y, c = blockIdx.x;   // 32 chunks x 128 rows
  const int d = threadIdx.x * 4;
  f32x4 s = {0.f, 0.f, 0.f, 0.f};
  const bf16* base = x + ((size_t)b * 4096 + (size_t)c * 128) * 1024 + d;
  for (int i = 0; i < 128; ++i) {
    bf16x4 v = *(const bf16x4*)(base + (size_t)i * 1024);
    s[0] += (float)v[0]; s[1] += (float)v[1];
    s[2] += (float)v[2]; s[3] += (float)v[3];
  }
  *(f32x4*)(part + ((size_t)(b * 32 + c)) * 1024 + d) = s;
}

// ---------------- kernel 3: router logits -> softmax probs (1 block/batch) ----------------
__global__ __launch_bounds__(256) void k_router(const float* __restrict__ part,
                                                const float* __restrict__ rw,
                                                const float* __restrict__ rb,
                                                float* __restrict__ probs,
                                                float* __restrict__ aux) {
  const int b = blockIdx.x;
  const int t = threadIdx.x;
  __shared__ float red[4];
  __shared__ float lg[3];
  f32x4 cs = {0.f, 0.f, 0.f, 0.f};
  #pragma unroll 8
  for (int c = 0; c < 32; ++c)
    cs += *(const f32x4*)(part + ((size_t)(b * 32 + c)) * 1024 + t * 4);
  for (int e = 0; e < 3; ++e) {
    float dot = cs[0] * rw[(t*4+0)*3+e] + cs[1] * rw[(t*4+1)*3+e]
              + cs[2] * rw[(t*4+2)*3+e] + cs[3] * rw[(t*4+3)*3+e];
    for (int off = 32; off; off >>= 1) dot += __shfl_down(dot, off);
    if ((t & 63) == 0) red[t >> 6] = dot;
    __syncthreads();
    if (t == 0) lg[e] = (red[0]+red[1]+red[2]+red[3]) * (1.0f/4096.0f) + rb[e];
    __syncthreads();
  }
  if (t == 0) {
    float m = fmaxf(lg[0], fmaxf(lg[1], lg[2]));
    float p0 = __expf(lg[0]-m), p1 = __expf(lg[1]-m), p2 = __expf(lg[2]-m);
    float inv = 1.0f / (p0 + p1 + p2);
    probs[b*3+0] = p0*inv; probs[b*3+1] = p1*inv; probs[b*3+2] = p2*inv;
    if (b == 0) *aux = 0.0f;
  }
}

// ------- kernel 4: mix experts by probs + transpose -> [B][N][K] bf16 -------
__global__ __launch_bounds__(256) void k_mixT(const float* __restrict__ W,  // [3][1024][Ncols]
                                              const float* __restrict__ probs,
                                              bf16* __restrict__ out,       // [8][Ncols][1024]
                                              int Ncols) {
  const int b = blockIdx.z;
  const int i0 = blockIdx.y * 64;   // K dim (1024)
  const int j0 = blockIdx.x * 64;   // N dim (Ncols)
  const float p0 = probs[b*3+0], p1 = probs[b*3+1], p2 = probs[b*3+2];
  __shared__ float tile[64][68];
  const int t = threadIdx.x;
  const int jl = (t & 15) * 4;
  const size_t estr = (size_t)1024 * Ncols;
  for (int ii = 0; ii < 4; ++ii) {
    int il = (t >> 4) + ii * 16;
    const float* src = W + (size_t)(i0 + il) * Ncols + (j0 + jl);
    f32x4 v0 = *(const f32x4*)(src);
    f32x4 v1 = *(const f32x4*)(src + estr);
    f32x4 v2 = *(const f32x4*)(src + 2 * estr);
    f32x4 v = p0 * v0 + p1 * v1 + p2 * v2;
    tile[il][jl+0] = v[0]; tile[il][jl+1] = v[1];
    tile[il][jl+2] = v[2]; tile[il][jl+3] = v[3];
  }
  __syncthreads();
  bf16* ob = out + (size_t)b * Ncols * 1024;
  const int il2 = (t & 15) * 4;
  for (int jj = 0; jj < 4; ++jj) {
    int jl2 = (t >> 4) + jj * 16;
    bf16x4 o;
    o[0] = (bf16)tile[il2+0][jl2]; o[1] = (bf16)tile[il2+1][jl2];
    o[2] = (bf16)tile[il2+2][jl2]; o[3] = (bf16)tile[il2+3][jl2];
    *(bf16x4*)(ob + (size_t)(j0 + jl2) * 1024 + (i0 + il2)) = o;
  }
}

// ========== 256x256 GEMM, BK=32, 4-slot counted-vmcnt pipeline ==========
// C[M,N] = A[M,K] @ Bt[N,K]^T, bf16 MFMA 16x16x32. BM=BN=256, BK=32, 8 waves
// (2M x 4N), 512 threads. LDS: 4 disjoint slots x (16KB A + 16KB B) = 128 KiB.
// Pipeline: tile t reads slot t%4; stage(t+3) writes slot (t+3)%4 = (t-1)%4,
// whose reads retired before the previous barrier -> no overwrite hazard ever.
// Tile end: counted s_waitcnt vmcnt(8) (completes t+1's 4 loads, leaves
// t+2/t+3's 8 in flight) + SCHED0-sandwiched s_barrier. Raw s_barrier is NOT
// a compiler fence -> SCHED0 required on BOTH sides (round-0 bug: post-barrier
// stages hoisted above s_barrier, racing slow waves' ds_reads).
// LDS layout (BK=32, 64B rows can't span 32 banks): pair rows into 128B lines;
// granule (r,g) of the 256x32 tile stored at line r2=r>>1, slot
// s = (((r&1)<<2)|g) ^ (r2&7). 16-row b128 fragment read -> 32 banks, 2-way (free).
// RULE #20: all acc[]/a[]/b[] indices compile-time constant.
// EPI 0: B rows permuted so hid (g=0,1) and gate (g=2,3) of the SAME j are
//        in-thread. EPI 1: LDS-retiled coalesced f32x4 epilogue + fp32 addend.
template<int EPI>
__global__ __launch_bounds__(512, 1) void k_gemm256(const bf16* __restrict__ A,
                                                    const bf16* __restrict__ Bt,
                                                    const float* __restrict__ addend,
                                                    float* __restrict__ Cout,
                                                    bf16* __restrict__ pa,
                                                    bf16* __restrict__ pb,
                                                    int M, int N, int K) {
  const int bz = blockIdx.z;
  // bijective XCD swizzle within the z-slice (nwg % 8 == 0 at both call sites)
  const int nx = gridDim.x;
  const int nwg = nx * gridDim.y;
  const int orig = blockIdx.y * nx + blockIdx.x;
  const int swz = (orig & 7) * (nwg >> 3) + (orig >> 3);
  const int tm = swz / nx, tn = swz % nx;

  __shared__ __align__(16) char smem[131072];
  const int tid = threadIdx.x;
  const int lane = tid & 63, w = tid >> 6;
  const int l15 = lane & 15, quad = lane >> 4;
  const int wm = (w >> 2) * 128;        // wave M-half base in tile
  const int wn = (w & 3) * 64;          // wave N-quarter base in tile

  const bf16* Ab  = A  + (size_t)bz * M * K;
  const bf16* Btb = Bt + (size_t)bz * N * K;

  auto browf = [&](int c) -> int {
    if constexpr (EPI == 0) {
      // tile col c -> WgT row: j = tn*128 + (c>>6)*32 + (c&31); gate iff (c&63)>=32
      return tn * 128 + ((c >> 6) * 32) + (c & 31) + (((c & 63) >= 32) ? 1024 : 0);
    } else {
      return tn * 256 + c;
    }
  };

  // ---- staging descriptors (per-lane, tile-invariant) ----
  // LDS granule index gsl = half*512 + tid; line r2 = gsl>>3, slot s = gsl&7.
  // Line r2 slot s holds g8 = s ^ (r2&7) -> row parity g8>>2, k-granule g8&3.
  // half offset 64 lines: (64+r2)&7 == r2&7, so g8 identical for both halves.
  const int s7  = tid & 7;
  const int r2a = tid >> 3;                 // 0..63
  const int g8v = s7 ^ (r2a & 7);
  const int par = g8v >> 2;                 // row parity
  const int gk  = g8v & 3;                  // k-granule (8 bf16)
  const int rl0 = 2 * r2a + par;            // local row, half 0 (0..127)
  const int rl1 = 128 + rl0;                // half 1 (128..255)

  const bf16* aSrc0 = Ab + (size_t)(tm*256 + rl0) * K + gk * 8;
  const bf16* aSrc1 = Ab + (size_t)(tm*256 + rl1) * K + gk * 8;
  const bf16* bSrc0 = Btb + (size_t)browf(rl0) * K + gk * 8;
  const bf16* bSrc1 = Btb + (size_t)browf(rl1) * K + gk * 8;

  // slot layout: slot*32768; A at +0 (2 halves of 8KB), B at +16384
  auto stage = [&](int slot, int u) {
    char* base = smem + slot * 32768;
    load16_lds(aSrc0 + u*32, base + tid*16);
    load16_lds(aSrc1 + u*32, base + 8192 + tid*16);
    load16_lds(bSrc0 + u*32, base + 16384 + tid*16);
    load16_lds(bSrc1 + u*32, base + 24576 + tid*16);
  };

  // ---- fragment read offsets (tile-invariant bytes within a slot) ----
  int offA[8], offB[4];
  #pragma unroll
  for (int f = 0; f < 8; ++f) {
    const int m = wm + (f >> 2) * 64 + (f & 3) * 16 + l15;
    const int r2 = m >> 1;
    offA[f] = r2 * 128 + (((((m & 1) << 2) | quad)) ^ (r2 & 7)) * 16;
  }
  #pragma unroll
  for (int f = 0; f < 4; ++f) {
    const int n = wn + (f >> 1) * 32 + (f & 1) * 16 + l15;
    const int r2 = n >> 1;
    offB[f] = r2 * 128 + (((((n & 1) << 2) | quad)) ^ (r2 & 7)) * 16;
  }

  f32x4 acc[8][4] = {};
  bf16x8 a[8], b[4];

  const int NT = K >> 5;   // K-tiles of 32 (requires NT >= 3; K=1024 -> 32)

  // prologue: stage tiles 0,1,2 (12 loads); complete tile 0 (leave 8 in flight)
  stage(0, 0); stage(1, 1); stage(2, 2);
  SCHED0();
  asm volatile("s_waitcnt vmcnt(8)" ::: "memory");
  SCHED0(); SBAR(); SCHED0();

  for (int t = 0; t < NT; ++t) {
    const int slot = t & 3;
    if (t + 3 < NT) stage((t + 3) & 3, t + 3);
    const char* ba = smem + slot * 32768;
    const char* bbp = ba + 16384;
    #pragma unroll
    for (int f = 0; f < 8; ++f) a[f] = *(const bf16x8*)(ba + offA[f]);
    #pragma unroll
    for (int f = 0; f < 4; ++f) b[f] = *(const bf16x8*)(bbp + offB[f]);
    #pragma unroll
    for (int f = 0; f < 8; ++f)
      #pragma unroll
      for (int g = 0; g < 4; ++g)
        acc[f][g] = __builtin_amdgcn_mfma_f32_16x16x32_bf16(a[f], b[g], acc[f][g], 0, 0, 0);
    if (t + 1 < NT) {
      SCHED0();
      const int rem = NT - 2 - t;   // tiles still in flight after t+1 completes
      if (rem >= 2)      { asm volatile("s_waitcnt vmcnt(8)" ::: "memory"); }
      else if (rem == 1) { asm volatile("s_waitcnt vmcnt(4)" ::: "memory"); }
      else               { asm volatile("s_waitcnt vmcnt(0)" ::: "memory"); }
      SCHED0(); SBAR(); SCHED0();
    }
  }
  __syncthreads();   // retire last tile's reads before any smem reuse

  if constexpr (EPI == 0) {
    // fused activation; in-thread pairing: hid = acc[f][g], gate = acc[f][g+2]
    bf16* Aab = pa + (size_t)bz * M * 1024;
    bf16* Bab = pb + (size_t)bz * M * 1024;
    const int jb = tn * 128 + (w & 3) * 32;
    const int rb = tm * 256 + wm;
    #pragma unroll
    for (int mi = 0; mi < 8; ++mi)
      #pragma unroll
      for (int ni = 0; ni < 2; ++ni)
        #pragma unroll
        for (int r = 0; r < 4; ++r) {
          const int srow = rb + mi * 16 + quad * 4 + r;
          float hid = acc[mi][ni][r];
          float gt  = acc[mi][ni + 2][r];
          float z = sigmoidf_(gt);
          float av = 1.0f - z;
          float gv = (hid >= 0.0f) ? (hid + 0.5f) : sigmoidf_(hid);
          float bv = z * gv;
          size_t oidx = (size_t)srow * 1024 + jb + ni * 16 + l15;
          Aab[oidx] = (bf16)av;
          Bab[oidx] = (bf16)bv;
        }
  } else {
    // LDS-retiled coalesced epilogue: 8 passes of 32 rows; ST=260 keeps 16B align.
    // FULLY UNROLLED (p compile-time) so every acc[] index is static (rule #20).
    float* sC = (float*)smem;
    const int ST = 260;
    float* C = Cout + (size_t)bz * M * N;
    const float* Ain = addend + (size_t)bz * M * N;
    #pragma unroll
    for (int p = 0; p < 8; ++p) {
      if ((w >> 2) == (p >> 2)) {
        const int mi0 = (p & 3) * 2;
        #pragma unroll
        for (int mm = 0; mm < 2; ++mm)
          #pragma unroll
          for (int nt_ = 0; nt_ < 4; ++nt_)
            #pragma unroll
            for (int r = 0; r < 4; ++r) {
              const int rl = mm * 16 + quad * 4 + r;
              sC[rl * ST + (w & 3) * 64 + nt_ * 16 + l15] = acc[mi0 + mm][nt_][r];
            }
      }
      __syncthreads();
      #pragma unroll
      for (int i = 0; i < 4; ++i) {
        const int v = i * 512 + tid;
        const int rl = v >> 6, c4 = (v & 63) * 4;
        const int grow = tm * 256 + p * 32 + rl;
        const int gcol = tn * 256 + c4;
        f32x4 cv = *(f32x4*)(sC + rl * ST + c4);
        f32x4 ad = *(const f32x4*)(Ain + (size_t)grow * N + gcol);
        *(f32x4*)(C + (size_t)grow * N + gcol) = cv + ad;
      }
      __syncthreads();
    }
  }
}

// pass 1: per-chunk (prodA, scanB) summaries. chunks of 64 steps.
__global__ __launch_bounds__(256) void k_scan1(const bf16* __restrict__ Aab,
                                               const bf16* __restrict__ Bab,
                                               float* __restrict__ cA,
                                               float* __restrict__ cB) {
  const int b = blockIdx.y, c = blockIdx.x;
  const int d = threadIdx.x * 4;
  f32x4 A = {1.f, 1.f, 1.f, 1.f}, Bv = {0.f, 0.f, 0.f, 0.f};
  const size_t base = ((size_t)(b * 4096 + c * 64)) * 1024 + d;
  #pragma unroll 4
  for (int i = 0; i < 64; ++i) {
    bf16x4 av = *(const bf16x4*)(Aab + base + (size_t)i * 1024);
    bf16x4 bv = *(const bf16x4*)(Bab + base + (size_t)i * 1024);
    #pragma unroll
    for (int j = 0; j < 4; ++j) {
      float a = (float)av[j], bb = (float)bv[j];
      A[j] *= a; Bv[j] = a * Bv[j] + bb;
    }
  }
  *(f32x4*)(cA + ((size_t)(b * 64 + c)) * 1024 + d) = A;
  *(f32x4*)(cB + ((size_t)(b * 64 + c)) * 1024 + d) = Bv;
}

// pass 2: chunk-level prefix; writes per-chunk entry state + new_state
__global__ __launch_bounds__(256) void k_scan2(const float* __restrict__ cA,
                                               const float* __restrict__ cB,
                                               const float* __restrict__ state,
                                               float* __restrict__ hin,
                                               float* __restrict__ ns) {
  const int gid = blockIdx.x * 256 + threadIdx.x;  // 8192 channels
  const int b = gid >> 10, d = gid & 1023;
  float h = state[gid];
  for (int c0 = 0; c0 < 64; c0 += 8) {
    float ar[8], br[8];
    #pragma unroll
    for (int i = 0; i < 8; ++i) {
      size_t idx = (((size_t)(b * 64 + c0 + i)) << 10) + d;
      ar[i] = cA[idx]; br[i] = cB[idx];
    }
    #pragma unroll
    for (int i = 0; i < 8; ++i) {
      size_t idx = (((size_t)(b * 64 + c0 + i)) << 10) + d;
      hin[idx] = h;
      h = ar[i] * h + br[i];
    }
  }
  ns[gid] = h;
}

// pass 3: replay chunk with known entry state, write h (bf16)
__global__ __launch_bounds__(256) void k_scan3(const bf16* __restrict__ Aab,
                                               const bf16* __restrict__ Bab,
                                               const float* __restrict__ hin,
                                               bf16* __restrict__ hq) {
  const int b = blockIdx.y, c = blockIdx.x;
  const int d = threadIdx.x * 4;
  f32x4 h = *(const f32x4*)(hin + ((size_t)(b * 64 + c)) * 1024 + d);
  const size_t base = ((size_t)(b * 4096 + c * 64)) * 1024 + d;
  bf16* ob = hq + base;
  #pragma unroll 4
  for (int i = 0; i < 64; ++i) {
    bf16x4 av = *(const bf16x4*)(Aab + base + (size_t)i * 1024);
    bf16x4 bv = *(const bf16x4*)(Bab + base + (size_t)i * 1024);
    bf16x4 o;
    #pragma unroll
    for (int j = 0; j < 4; ++j) {
      h[j] = (float)av[j] * h[j] + (float)bv[j];
      o[j] = (bf16)h[j];
    }
    *(bf16x4*)(ob + (size_t)i * 1024) = o;
  }
}

extern "C" void kernel_launch(void* const* d_in, const int* in_sizes, int n_in,
                              void* d_out, int out_size, void* d_ws, size_t ws_size,
                              hipStream_t stream) {
  const float* inputs   = (const float*)d_in[0];
  const float* state    = (const float*)d_in[1];
  const float* norm_w   = (const float*)d_in[2];
  const float* router_w = (const float*)d_in[3];
  const float* router_b = (const float*)d_in[4];
  const float* w_gh     = (const float*)d_in[5];
  const float* w_out    = (const float*)d_in[6];

  float* out = (float*)d_out;
  float* new_state = out + (size_t)8 * 4096 * 1024;
  float* aux = new_state + 8 * 1024;

  char* ws = (char*)d_ws;
  size_t off = 0;
  auto alloc = [&](size_t bytes) {
    char* p = ws + off;
    off = (off + bytes + 255) & ~(size_t)255;
    return p;
  };
  bf16*  x    = (bf16*)alloc((size_t)8 * 4096 * 1024 * 2);   // 64 MB
  bf16*  a_ar = (bf16*)alloc((size_t)8 * 4096 * 1024 * 2);   // 64 MB
  bf16*  b_ar = (bf16*)alloc((size_t)8 * 4096 * 1024 * 2);   // 64 MB
  bf16*  hq   = (bf16*)alloc((size_t)8 * 4096 * 1024 * 2);   // 64 MB
  bf16*  WgT  = (bf16*)alloc((size_t)8 * 2048 * 1024 * 2);   // 32 MB
  bf16*  WoT  = (bf16*)alloc((size_t)8 * 1024 * 1024 * 2);   // 16 MB
  float* part = (float*)alloc((size_t)8 * 32 * 1024 * 4);    // 1 MB
  float* probs = (float*)alloc(256);
  float* cA   = (float*)alloc((size_t)8 * 64 * 1024 * 4);    // 2 MB
  float* cB   = (float*)alloc((size_t)8 * 64 * 1024 * 4);
  float* hin  = (float*)alloc((size_t)8 * 64 * 1024 * 4);
  (void)in_sizes; (void)n_in; (void)out_size; (void)ws_size;

  k_rms_x <<<32768, 256, 0, stream>>>(inputs, norm_w, x);
  k_colsum<<<dim3(32, 8), 256, 0, stream>>>(x, part);
  k_router<<<8, 256, 0, stream>>>(part, router_w, router_b, probs, aux);
  k_mixT  <<<dim3(32, 16, 8), 256, 0, stream>>>(w_gh, probs, WgT, 2048);
  k_mixT  <<<dim3(16, 16, 8), 256, 0, stream>>>(w_out, probs, WoT, 1024);
  k_gemm256<0><<<dim3(8, 16, 8), 512, 0, stream>>>(x, WgT, nullptr, nullptr,
                                                   a_ar, b_ar, 4096, 2048, 1024);
  k_scan1 <<<dim3(64, 8), 256, 0, stream>>>(a_ar, b_ar, cA, cB);
  k_scan2 <<<32, 256, 0, stream>>>(cA, cB, state, hin, new_state);
  k_scan3 <<<dim3(64, 8), 256, 0, stream>>>(a_ar, b_ar, hin, hq);
  k_gemm256<1><<<dim3(4, 16, 8), 512, 0, stream>>>(hq, WoT, inputs, out,
                                                   nullptr, nullptr, 4096, 1024, 1024);
}